// Round 2
// baseline (52.549 us; speedup 1.0000x reference)
//
#include <hip/hip_runtime.h>
#include <math.h>

// Problem geometry (fixed by the reference).
constexpr int Bc = 32, Fc = 513, Tc = 1600;
constexpr int BLK = 128;                  // threads per block (2 waves)
constexpr int VEC = 4;                    // float4 per thread
constexpr int TT  = BLK * VEC;            // 512 t per block tile
constexpr int NTT = (Tc + TT - 1) / TT;   // 4 t-tiles (last partial: 64)
constexpr int FCH = 9;                    // f rows per block (513 = 57*9)
constexpr int NFC = (Fc + FCH - 1) / FCH; // 57 f-chunks
constexpr int NBLK = Bc * NFC * NTT;      // 7296 blocks
constexpr long long NTOT = (long long)Bc * Fc * Tc;  // 26,265,600

__device__ __forceinline__ float anti_wrap_f(float x) {
    // |x - round(x/2pi)*2pi|, round-half-even == jnp.round
    float r = rintf(x * 0.15915494309189535f);
    return fabsf(fmaf(-r, 6.283185307179586f, x));
}

// Reduce three per-thread floats across the block; result valid in thread 0.
__device__ __forceinline__ void block_reduce3(float& a, float& b, float& c) {
    #pragma unroll
    for (int off = 32; off > 0; off >>= 1) {
        a += __shfl_down(a, off);
        b += __shfl_down(b, off);
        c += __shfl_down(c, off);
    }
    __shared__ float sm[3][BLK / 64];
    const int lane = threadIdx.x & 63, wid = threadIdx.x >> 6;
    if (lane == 0) { sm[0][wid] = a; sm[1][wid] = b; sm[2][wid] = c; }
    __syncthreads();
    if (threadIdx.x == 0) {
        a = sm[0][0]; b = sm[1][0]; c = sm[2][0];
        #pragma unroll
        for (int w = 1; w < BLK / 64; ++w) {
            a += sm[0][w]; b += sm[1][w]; c += sm[2][w];
        }
    }
}

__global__ __launch_bounds__(BLK) void phase_main(
        const float* __restrict__ pr, const float* __restrict__ pg,
        float* __restrict__ partials,   // [3][NBLK] when two-stage
        float* __restrict__ out,        // atomic fallback target
        int use_atomic)
{
    const int tile = blockIdx.x;   // t tile
    const int fc   = blockIdx.y;   // f chunk
    const int b    = blockIdx.z;   // batch
    const int t0   = tile * TT + (int)threadIdx.x * VEC;
    const int f0   = fc * FCH;
    const int f1   = min(f0 + FCH, Fc);

    float s_ip = 0.f, s_gd = 0.f, s_ptd = 0.f;

    if (t0 < Tc) {  // Tc % VEC == 0, so a thread's 4 elems are all-valid or none
        const size_t baseb = (size_t)b * Fc * Tc + (size_t)t0;
        const float* ap = pr + baseb + (size_t)f0 * Tc;
        const float* gp = pg + baseb + (size_t)f0 * Tc;

        // Previous-row d (f-1 neighbor), carried in registers across the f loop.
        float4 pd;
        if (f0 == 0) {
            pd = make_float4(0.f, 0.f, 0.f, 0.f);  // implicit zero pad at f=-1
        } else {
            float4 a = *(const float4*)(ap - Tc);
            float4 g = *(const float4*)(gp - Tc);
            pd = make_float4(a.x - g.x, a.y - g.y, a.z - g.z, a.w - g.w);
        }

        // Software-pipelined: current row in regs, next row's loads in flight.
        float4 a = *(const float4*)ap;
        float4 g = *(const float4*)gp;
        float am1 = 0.f, gm1 = 0.f;
        if (t0 > 0) { am1 = ap[-1]; gm1 = gp[-1]; }

        for (int f = f0; f < f1; ++f) {
            const float* apn = ap + Tc;
            const float* gpn = gp + Tc;
            float4 an = make_float4(0.f, 0.f, 0.f, 0.f);
            float4 gn = make_float4(0.f, 0.f, 0.f, 0.f);
            float am1n = 0.f, gm1n = 0.f;
            if (f + 1 < f1) {                    // issue next-row loads early
                an = *(const float4*)apn;
                gn = *(const float4*)gpn;
                if (t0 > 0) { am1n = apn[-1]; gm1n = gpn[-1]; }
            }

            float  dm1 = am1 - gm1;              // d at t-1 (0 at global t==0)
            float4 d = make_float4(a.x - g.x, a.y - g.y, a.z - g.z, a.w - g.w);

            s_ip  += anti_wrap_f(d.x) + anti_wrap_f(d.y)
                   + anti_wrap_f(d.z) + anti_wrap_f(d.w);
            s_gd  += anti_wrap_f(pd.x - d.x) + anti_wrap_f(pd.y - d.y)
                   + anti_wrap_f(pd.z - d.z) + anti_wrap_f(pd.w - d.w);
            s_ptd += anti_wrap_f(dm1 - d.x) + anti_wrap_f(d.x - d.y)
                   + anti_wrap_f(d.y - d.z) + anti_wrap_f(d.z - d.w);

            pd = d;
            a = an; g = gn; am1 = am1n; gm1 = gm1n;
            ap = apn; gp = gpn;
        }
    }

    block_reduce3(s_ip, s_gd, s_ptd);

    if (threadIdx.x == 0) {
        if (use_atomic) {
            const float invN = (float)(1.0 / (double)NTOT);
            atomicAdd(out + 0, s_ip * invN);
            atomicAdd(out + 1, s_gd * invN);
            atomicAdd(out + 2, s_ptd * invN);
        } else {
            const int bid = (blockIdx.z * gridDim.y + blockIdx.y) * gridDim.x
                          + blockIdx.x;
            partials[0 * NBLK + bid] = s_ip;
            partials[1 * NBLK + bid] = s_gd;
            partials[2 * NBLK + bid] = s_ptd;
        }
    }
}

// One block per channel; block reduces NBLK partials.
__global__ __launch_bounds__(256) void phase_reduce(
        const float* __restrict__ partials, float* __restrict__ out)
{
    const int c = blockIdx.x;
    const int tid = threadIdx.x;
    float s = 0.f;
    for (int i = tid; i < NBLK; i += 256) s += partials[(size_t)c * NBLK + i];
    #pragma unroll
    for (int off = 32; off > 0; off >>= 1) s += __shfl_down(s, off);
    __shared__ float sm[4];
    const int lane = tid & 63, wid = tid >> 6;
    if (lane == 0) sm[wid] = s;
    __syncthreads();
    if (tid == 0) {
        float t = sm[0] + sm[1] + sm[2] + sm[3];
        out[c] = t * (float)(1.0 / (double)NTOT);
    }
}

__global__ void zero3(float* out) {
    if (threadIdx.x < 3) out[threadIdx.x] = 0.f;
}

extern "C" void kernel_launch(void* const* d_in, const int* in_sizes, int n_in,
                              void* d_out, int out_size, void* d_ws, size_t ws_size,
                              hipStream_t stream) {
    const float* pr = (const float*)d_in[0];
    const float* pg = (const float*)d_in[1];
    float* out = (float*)d_out;
    dim3 grid(NTT, NFC, Bc);

    if (ws_size >= (size_t)NBLK * 3 * sizeof(float)) {
        float* partials = (float*)d_ws;
        phase_main<<<grid, BLK, 0, stream>>>(pr, pg, partials, nullptr, 0);
        phase_reduce<<<3, 256, 0, stream>>>(partials, out);
    } else {
        zero3<<<1, 64, 0, stream>>>(out);
        phase_main<<<grid, BLK, 0, stream>>>(pr, pg, nullptr, out, 1);
    }
}

// Round 3
// 47.677 us; speedup vs baseline: 1.1022x; 1.1022x over previous
//
#include <hip/hip_runtime.h>
#include <math.h>

// Problem geometry (fixed by the reference).
constexpr int Bc = 32, Fc = 513, Tc = 1600;
constexpr int BLK = 128;                  // threads per block (2 waves)
constexpr int VEC = 4;                    // float4 per thread
constexpr int TT  = BLK * VEC;            // 512 t per block tile
constexpr int NTT = (Tc + TT - 1) / TT;   // 4 t-tiles (last partial: 64)
constexpr int FCH = 27;                   // f rows per block (513 = 19*27)
constexpr int NFC = Fc / FCH;             // 19 f-chunks (exact)
constexpr int NBLK = Bc * NFC * NTT;      // 2432 blocks
constexpr long long NTOT = (long long)Bc * Fc * Tc;  // 26,265,600

__device__ __forceinline__ float anti_wrap_f(float x) {
    // |x - round(x/2pi)*2pi|, round-half-even == jnp.round
    float r = rintf(x * 0.15915494309189535f);
    return fabsf(fmaf(-r, 6.283185307179586f, x));
}

// Reduce three per-thread floats across the block; result valid in thread 0.
__device__ __forceinline__ void block_reduce3(float& a, float& b, float& c) {
    #pragma unroll
    for (int off = 32; off > 0; off >>= 1) {
        a += __shfl_down(a, off);
        b += __shfl_down(b, off);
        c += __shfl_down(c, off);
    }
    __shared__ float sm[3][BLK / 64];
    const int lane = threadIdx.x & 63, wid = threadIdx.x >> 6;
    if (lane == 0) { sm[0][wid] = a; sm[1][wid] = b; sm[2][wid] = c; }
    __syncthreads();
    if (threadIdx.x == 0) {
        a = sm[0][0]; b = sm[1][0]; c = sm[2][0];
        #pragma unroll
        for (int w = 1; w < BLK / 64; ++w) {
            a += sm[0][w]; b += sm[1][w]; c += sm[2][w];
        }
    }
}

__global__ __launch_bounds__(BLK) void phase_main(
        const float* __restrict__ pr, const float* __restrict__ pg,
        float* __restrict__ partials,   // [3][NBLK] when two-stage
        float* __restrict__ out,        // atomic fallback target
        int use_atomic)
{
    const int tile = blockIdx.x;   // t tile
    const int fc   = blockIdx.y;   // f chunk
    const int b    = blockIdx.z;   // batch
    const int t0   = tile * TT + (int)threadIdx.x * VEC;
    const int f0   = fc * FCH;
    const int f1   = f0 + FCH;     // 513 = 19*27 exact
    const int lane = (int)threadIdx.x & 63;
    // Only lane 0 of each wave loads the t-1 boundary scalar; other lanes
    // get it via shfl_up of the neighbor's d.w.
    const bool edge = (lane == 0) && (t0 > 0);

    float s_ip = 0.f, s_gd = 0.f, s_ptd = 0.f;

    if (t0 < Tc) {  // Tc % VEC == 0, so a thread's 4 elems are all-valid or none
        const size_t baseb = (size_t)b * Fc * Tc + (size_t)t0;
        const float* ap = pr + baseb + (size_t)f0 * Tc;
        const float* gp = pg + baseb + (size_t)f0 * Tc;

        // Previous-row d (f-1 neighbor), carried in registers across the f loop.
        float4 pd;
        if (f0 == 0) {
            pd = make_float4(0.f, 0.f, 0.f, 0.f);  // implicit zero pad at f=-1
        } else {
            float4 a = *(const float4*)(ap - Tc);
            float4 g = *(const float4*)(gp - Tc);
            pd = make_float4(a.x - g.x, a.y - g.y, a.z - g.z, a.w - g.w);
        }

        // Depth-2 software pipeline: rows f (C) and f+1 (N) resident, row f+2
        // being fetched each iteration (clamped pointer, no branch).
        float4 aC = *(const float4*)ap;
        float4 gC = *(const float4*)gp;
        float4 aN = *(const float4*)(ap + Tc);
        float4 gN = *(const float4*)(gp + Tc);
        float amC = 0.f, gmC = 0.f, amN = 0.f, gmN = 0.f;
        if (edge) {
            amC = ap[-1];      gmC = gp[-1];
            amN = ap[Tc - 1];  gmN = gp[Tc - 1];
        }

        #pragma unroll 3
        for (int f = f0; f < f1; ++f) {
            // Prefetch row f+2, clamped to f (re-read, L1 hit, discarded).
            const bool ok = (f + 2 < f1);
            const float* ap2 = ok ? (ap + 2 * (size_t)Tc) : ap;
            const float* gp2 = ok ? (gp + 2 * (size_t)Tc) : gp;
            float4 aP = *(const float4*)ap2;
            float4 gP = *(const float4*)gp2;
            float amP = 0.f, gmP = 0.f;
            if (edge) { amP = ap2[-1]; gmP = gp2[-1]; }

            float4 d = make_float4(aC.x - gC.x, aC.y - gC.y,
                                   aC.z - gC.z, aC.w - gC.w);
            float dwm = __shfl_up(d.w, 1);          // lane l-1's d[t0-1]
            float dm1 = (lane == 0) ? (amC - gmC) : dwm;  // 0 at global t==0

            s_ip  += anti_wrap_f(d.x) + anti_wrap_f(d.y)
                   + anti_wrap_f(d.z) + anti_wrap_f(d.w);
            s_gd  += anti_wrap_f(pd.x - d.x) + anti_wrap_f(pd.y - d.y)
                   + anti_wrap_f(pd.z - d.z) + anti_wrap_f(pd.w - d.w);
            s_ptd += anti_wrap_f(dm1 - d.x) + anti_wrap_f(d.x - d.y)
                   + anti_wrap_f(d.y - d.z) + anti_wrap_f(d.z - d.w);

            pd = d;
            aC = aN; gC = gN; amC = amN; gmC = gmN;
            aN = aP; gN = gP; amN = amP; gmN = gmP;
            ap += Tc; gp += Tc;
        }
    }

    block_reduce3(s_ip, s_gd, s_ptd);

    if (threadIdx.x == 0) {
        if (use_atomic) {
            const float invN = (float)(1.0 / (double)NTOT);
            atomicAdd(out + 0, s_ip * invN);
            atomicAdd(out + 1, s_gd * invN);
            atomicAdd(out + 2, s_ptd * invN);
        } else {
            const int bid = (blockIdx.z * gridDim.y + blockIdx.y) * gridDim.x
                          + blockIdx.x;
            partials[0 * NBLK + bid] = s_ip;
            partials[1 * NBLK + bid] = s_gd;
            partials[2 * NBLK + bid] = s_ptd;
        }
    }
}

// One block per channel; block reduces NBLK partials.
__global__ __launch_bounds__(256) void phase_reduce(
        const float* __restrict__ partials, float* __restrict__ out)
{
    const int c = blockIdx.x;
    const int tid = threadIdx.x;
    float s = 0.f;
    for (int i = tid; i < NBLK; i += 256) s += partials[(size_t)c * NBLK + i];
    #pragma unroll
    for (int off = 32; off > 0; off >>= 1) s += __shfl_down(s, off);
    __shared__ float sm[4];
    const int lane = tid & 63, wid = tid >> 6;
    if (lane == 0) sm[wid] = s;
    __syncthreads();
    if (tid == 0) {
        float t = sm[0] + sm[1] + sm[2] + sm[3];
        out[c] = t * (float)(1.0 / (double)NTOT);
    }
}

__global__ void zero3(float* out) {
    if (threadIdx.x < 3) out[threadIdx.x] = 0.f;
}

extern "C" void kernel_launch(void* const* d_in, const int* in_sizes, int n_in,
                              void* d_out, int out_size, void* d_ws, size_t ws_size,
                              hipStream_t stream) {
    const float* pr = (const float*)d_in[0];
    const float* pg = (const float*)d_in[1];
    float* out = (float*)d_out;
    dim3 grid(NTT, NFC, Bc);

    if (ws_size >= (size_t)NBLK * 3 * sizeof(float)) {
        float* partials = (float*)d_ws;
        phase_main<<<grid, BLK, 0, stream>>>(pr, pg, partials, nullptr, 0);
        phase_reduce<<<3, 256, 0, stream>>>(partials, out);
    } else {
        zero3<<<1, 64, 0, stream>>>(out);
        phase_main<<<grid, BLK, 0, stream>>>(pr, pg, nullptr, out, 1);
    }
}